// Round 11
// baseline (126.084 us; speedup 1.0000x reference)
//
#include <hip/hip_runtime.h>

#define A_TOT 8400
#define NCLS  80
#define MGT   64
#define TK    13
#define EPS7  1e-7f
#define EPS9  1e-9f
#define INV_PI2 0.4052847345693511f     // 4/pi^2
#define BTH   1024                      // k_resolveB threads / anchor window
#define NWIN  ((A_TOT + BTH - 1) / BTH) // 9 windows per batch

__device__ __forceinline__ float ciou_clip(
    float gx1, float gy1, float gx2, float gy2, float ga, float area1,
    float px1, float py1, float px2, float py2, float pa)
{
  float w2 = px2 - px1, h2 = py2 - py1 + EPS7;
  float iw = fmaxf(fminf(gx2, px2) - fmaxf(gx1, px1), 0.f);
  float ih = fmaxf(fminf(gy2, py2) - fmaxf(gy1, py1), 0.f);
  float inter = iw * ih;
  float uni = area1 + w2 * h2 - inter + EPS7;
  float iou = inter / uni;
  float cw = fmaxf(gx2, px2) - fminf(gx1, px1);
  float ch = fmaxf(gy2, py2) - fminf(gy1, py1);
  float c2 = cw * cw + ch * ch + EPS7;
  float dx = px1 + px2 - gx1 - gx2;
  float dy = py1 + py2 - gy1 - gy2;
  float rho2 = (dx * dx + dy * dy) * 0.25f;
  float dd = pa - ga;
  float v = INV_PI2 * dd * dd;
  float alpha = v / (v - iou + (1.f + EPS7));
  float c = iou - (rho2 / c2 + v * alpha);
  return fmaxf(c, 0.f);   // overlaps = ciou.clip(0)
}

__device__ __forceinline__ unsigned long long wmax64(unsigned long long k) {
#pragma unroll
  for (int s = 32; s > 0; s >>= 1) {
    unsigned long long o = __shfl_xor(k, s, 64);
    k = (o > k) ? o : k;
  }
  return k;
}

// ============ Node A: per-(b,m) top-13 -> index lists + (am, ov) ============
// Zeroes its OWN pos_al/pos_ov slot (no memset node). Candidate set =
// {anchors 0..255} U {in-box grid rectangles per scale}; provably contains
// lax.top_k(metrics,13) (round-5 argument). For the 13 winners, stores
// (align_metric, overlap) so node B never recomputes CIoU for single-gt
// anchors.
__global__ __launch_bounds__(256)
void k_topkA(const float* __restrict__ pd_scores,
             const float* __restrict__ pd_bboxes,
             const float* __restrict__ anc,
             const int* __restrict__ gt_labels,
             const float* __restrict__ gt_bboxes,
             const float* __restrict__ mask_gt,
             int* __restrict__ topk_idx,
             float2* __restrict__ topk_av,
             unsigned int* __restrict__ pos_al,
             unsigned int* __restrict__ pos_ov)
{
  int row = blockIdx.x;                 // b*MGT + m
  int tid = threadIdx.x, lane = tid & 63, wid = tid >> 6;
  __shared__ unsigned long long sk[4 * TK];

  if (tid == 0) { pos_al[row] = 0u; pos_ov[row] = 0u; }  // own slot only

  if (mask_gt[row] <= 0.f) {            // block-uniform
    if (tid < TK) topk_idx[row * TK + tid] = -1;
    return;
  }
  int b = row >> 6;

  float4 g = ((const float4*)gt_bboxes)[row];
  float ga = atanf((g.z - g.x) / (g.w - g.y + EPS7));
  float area1 = (g.z - g.x) * (g.w - g.y + EPS7);
  int label = gt_labels[row];
  const float*  ps   = pd_scores + (size_t)b * A_TOT * NCLS + label;
  const float4* pb   = (const float4*)(pd_bboxes + (size_t)b * A_TOT * 4);
  const float2* anc2 = (const float2*)anc;

  unsigned long long l[TK];
#pragma unroll
  for (int k = 0; k < TK; ++k) l[k] = 0ULL;

  auto insert = [&](unsigned long long key) {
    if (key > l[TK - 1]) {
#pragma unroll
      for (int j = TK - 1; j > 0; --j) {
        unsigned long long prev = l[j - 1];
        l[j] = (key > prev) ? prev : ((key > l[j]) ? key : l[j]);
      }
      l[0] = (key > l[0]) ? key : l[0];
    }
  };
  auto eval_inbox = [&](int a) -> unsigned long long {
    float4 p = pb[a];
    float pa = atanf((p.z - p.x) / (p.w - p.y + EPS7));
    float ov = ciou_clip(g.x, g.y, g.z, g.w, ga, area1, p.x, p.y, p.z, p.w, pa);
    float o2 = ov * ov;
    float metric = ps[(size_t)a * NCLS] * (o2 * o2 * o2);
    return (((unsigned long long)__float_as_uint(metric)) << 32) |
           (unsigned long long)(~(unsigned)a);
  };

  // pass 1: anchors 0..255 (zero-pool for tie-fills; covers rect cells < 256)
  {
    int a = tid;
    float2 an = anc2[a];
    float dmin = fminf(fminf(an.x - g.x, an.y - g.y), fminf(g.z - an.x, g.w - an.y));
    unsigned long long key = (unsigned long long)(~(unsigned)a);
    if (dmin > EPS9) key = eval_inbox(a);
    insert(key);
  }

  // pass 2: per-scale in-box rectangles (closed form; skip a<256)
  const int   ns[3] = {80, 40, 20};
  const float ss[3] = {8.f, 16.f, 32.f};
  const int   bb[3] = {0, 6400, 8000};
#pragma unroll
  for (int sc = 0; sc < 3; ++sc) {
    int n = ns[sc]; float s = ss[sc]; int base = bb[sc];
    float inv_s = 1.f / s;              // power of two: exact
    int xlo = max(0,     (int)floorf(g.x * inv_s - 0.5f));
    int xhi = min(n - 1, (int)ceilf (g.z * inv_s - 0.5f));
    int ylo = max(0,     (int)floorf(g.y * inv_s - 0.5f));
    int yhi = min(n - 1, (int)ceilf (g.w * inv_s - 0.5f));
    int nx = xhi - xlo + 1, ny = yhi - ylo + 1;
    if (nx <= 0 || ny <= 0) continue;
    int tot = nx * ny;
    float invnx = 1.f / (float)nx;
    for (int r = tid; r < tot; r += 256) {
      int q  = (int)floorf(((float)r + 0.5f) * invnx);
      int ix = xlo + (r - q * nx);
      int iy = ylo + q;
      int a = base + iy * n + ix;
      if (a < 256) continue;
      float ax = ((float)ix + 0.5f) * s;
      float ay = ((float)iy + 0.5f) * s;
      float dmin = fminf(fminf(ax - g.x, ay - g.y), fminf(g.z - ax, g.w - ay));
      if (dmin > EPS9) insert(eval_inbox(a));
      // out-of-box a>=256 never reaches top-13: 256 pass-1 keys dominate.
    }
  }

  // per-wave top-13 extraction (keys unique), cross-wave merge by wave 0
  unsigned long long wres = 0ULL;
#pragma unroll
  for (int r = 0; r < TK; ++r) {
    unsigned long long w = wmax64(l[0]);
    if (lane == r) wres = w;
    if (l[0] == w) {
#pragma unroll
      for (int j = 0; j < TK - 1; ++j) l[j] = l[j + 1];
      l[TK - 1] = 0ULL;
    }
  }
  if (lane < TK) sk[wid * TK + lane] = wres;
  __syncthreads();

  if (wid == 0) {
    unsigned long long c = (lane < 4 * TK) ? sk[lane] : 0ULL;
    unsigned long long res = 0ULL;
#pragma unroll
    for (int r = 0; r < TK; ++r) {
      unsigned long long w = wmax64(c);
      if (lane == r) res = w;
      if (c == w) c = 0ULL;
    }
    if (lane < TK) {
      unsigned a = ~(unsigned)res;
      float2 an = anc2[a];
      float dmin = fminf(fminf(an.x - g.x, an.y - g.y), fminf(g.z - an.x, g.w - an.y));
      bool ok = dmin > EPS9;            // mask_topk * mask_in_gts
      float am = 0.f, ov = 0.f;
      if (ok) {                         // recompute ov (1 CIoU/lane, 13 lanes)
        float4 p = pb[a];
        float pa = atanf((p.z - p.x) / (p.w - p.y + EPS7));
        ov = ciou_clip(g.x, g.y, g.z, g.w, ga, area1, p.x, p.y, p.z, p.w, pa);
        am = __uint_as_float((unsigned)(res >> 32));
      }
      topk_idx[row * TK + lane] = ok ? (int)a : -1;
      topk_av[row * TK + lane] = make_float2(am, ov);
    }
  }
}

// ============ Node B: windowed resolve, table-driven (no CIoU for singles) ====
// Grid = bs * NWIN blocks; block (b, s) owns anchors [s*BTH, s*BTH+BTH).
// Scans the batch's 832 list entries (1 thread each): scatters cnt|m into a
// 4KB LDS map and (am, ov) into an 8KB LDS value map (unique writer iff
// cnt==1, garbage-but-unused otherwise). cnt==1 anchors resolve by pure
// lookup + 2 global atomicMax. cnt>1 anchors (rare) use the whole-wave
// ballot argmax over all 64 LDS-staged gts (first-max key
// (fbits(ov)<<6)|(63-m)). Emits pk = {am | fg|lab|tgt}.
__global__ __launch_bounds__(BTH)
void k_resolveB(const float* __restrict__ pd_scores,
                const float* __restrict__ pd_bboxes,
                const int* __restrict__ gt_labels,
                const float* __restrict__ gt_bboxes,
                const int* __restrict__ topk_idx,
                const float2* __restrict__ topk_av,
                unsigned int* __restrict__ pos_al,
                unsigned int* __restrict__ pos_ov,
                unsigned long long* __restrict__ pk)
{
  int b = blockIdx.x / NWIN;
  int s = blockIdx.x - b * NWIN;
  int lo = s * BTH;
  int tid = threadIdx.x, lane = tid & 63;

  __shared__ unsigned int cntm[BTH];            // (cnt<<16) | sum(m)
  __shared__ float2 av[BTH];                    // (am, ov) for cnt==1 anchors
  __shared__ float4 sg[MGT];
  __shared__ float  sga[MGT], sarea[MGT];
  __shared__ int    slabm[MGT];

  cntm[tid] = 0u;
  if (tid < MGT) {
    float4 g = ((const float4*)gt_bboxes)[b * MGT + tid];
    sg[tid] = g;
    sga[tid] = atanf((g.z - g.x) / (g.w - g.y + EPS7));
    sarea[tid] = (g.z - g.x) * (g.w - g.y + EPS7);
    slabm[tid] = gt_labels[b * MGT + tid];
  }
  __syncthreads();

  if (tid < MGT * TK) {                 // 832 entries, one thread each
    int a = topk_idx[b * MGT * TK + tid];
    int r = a - lo;
    if (a >= 0 && r >= 0 && r < BTH) {
      atomicAdd(&cntm[r], (1u << 16) | (unsigned)(tid / TK));
      av[r] = topk_av[b * MGT * TK + tid];  // unique writer iff cnt==1
    }
  }
  __syncthreads();

  const float4* pb = (const float4*)pd_bboxes + (size_t)b * A_TOT;
  const float*  ps = pd_scores + (size_t)b * A_TOT * NCLS;

  int a = lo + tid;
  bool valid = a < A_TOT;
  unsigned cm = valid ? cntm[tid] : 0u;
  int cnt = (int)(cm >> 16);
  int mytgt = -1; float myam = 0.f;
  if (valid && cnt == 1) {              // pure table lookup — no CIoU/gather
    int m = (int)(cm & 0xffffu);
    float2 v = av[tid];
    myam = v.x;
    mytgt = m;
    atomicMax(pos_al + b * MGT + m, __float_as_uint(v.x));
    atomicMax(pos_ov + b * MGT + m, __float_as_uint(v.y));
  }
  // multi-gt anchors: whole-wave argmax over ALL 64 gts (first-max)
  float4 p = make_float4(0.f, 0.f, 0.f, 0.f);
  float pa = 0.f;
  if (valid && cnt > 1) {
    p = pb[a];
    pa = atanf((p.z - p.x) / (p.w - p.y + EPS7));
  }
  unsigned long long mb = __ballot(valid && cnt > 1);
  while (mb) {
    int src = __ffsll(mb) - 1; mb &= mb - 1;
    int   aa  = __shfl(a, src);
    float px1 = __shfl(p.x, src), py1 = __shfl(p.y, src);
    float px2 = __shfl(p.z, src), py2 = __shfl(p.w, src);
    float spa = __shfl(pa, src);
    float4 g = sg[lane];
    float ov = ciou_clip(g.x, g.y, g.z, g.w, sga[lane], sarea[lane],
                         px1, py1, px2, py2, spa);
    unsigned long long key =
        (((unsigned long long)__float_as_uint(ov)) << 6) | (unsigned)(63 - lane);
    unsigned long long w = wmax64(key);
    int   wl  = 63 - (int)(w & 63ULL);
    float wov = __uint_as_float((unsigned)(w >> 6));
    float am_s = 0.f;
    if (lane == wl) {                   // winner lane: its own gt data
      float o2 = wov * wov;
      am_s = ps[(size_t)aa * NCLS + slabm[wl]] * (o2 * o2 * o2);
      atomicMax(pos_al + b * MGT + wl, __float_as_uint(am_s));
      atomicMax(pos_ov + b * MGT + wl, __float_as_uint(wov));
    }
    am_s = __shfl(am_s, wl);
    if (lane == src) { mytgt = wl; myam = am_s; }
  }

  if (valid) {
    bool fg = mytgt >= 0;
    int tgt = fg ? mytgt : 0;
    int lab = slabm[tgt]; if (lab < 0) lab = 0;
    unsigned lov = (unsigned)tgt | ((unsigned)lab << 8) | ((fg ? 1u : 0u) << 24);
    pk[(size_t)b * A_TOT + a] =
        (((unsigned long long)__float_as_uint(myam)) << 32) | lov;
  }
}

// ============ Node C: norm + streaming output write ============
__global__ __launch_bounds__(256)
void k_writeC(const unsigned long long* __restrict__ pk,
              const unsigned int* __restrict__ pos_al,
              const unsigned int* __restrict__ pos_ov,
              const float* __restrict__ gt_bboxes,
              float* __restrict__ out, int total)
{
  __shared__ int   slab[256];
  __shared__ float snorm[256];
  int base = blockIdx.x * 256, tid = threadIdx.x;
  int t = base + tid;
  int nrows = total - base; if (nrows > 256) nrows = 256;
  size_t OFF_BOX = (size_t)total;
  size_t OFF_SCR = OFF_BOX + (size_t)total * 4;
  size_t OFF_FG  = OFF_SCR + (size_t)total * NCLS;
  size_t OFF_TGT = OFF_FG + (size_t)total;
  int lab = 0; float nrm = 0.f;
  if (t < total) {
    unsigned long long v = pk[t];
    unsigned lov = (unsigned)v;
    int tgt = (int)(lov & 0xffu);
    lab = (int)((lov >> 8) & 0xffu);
    bool fg = (lov >> 24) & 1u;
    int b = t / A_TOT;
    int gi = b * MGT + tgt;
    if (fg) {
      float am  = __uint_as_float((unsigned)(v >> 32));
      float pal = __uint_as_float(pos_al[gi]);
      float pov = __uint_as_float(pos_ov[gi]);
      nrm = am * pov / (pal + EPS9);    // pos tables are tiny -> L2-resident
    }
    float4 box = ((const float4*)gt_bboxes)[gi];
    out[t] = (float)lab;
    ((float4*)(out + OFF_BOX))[t] = box;
    out[OFF_FG + t]  = fg ? 1.f : 0.f;
    out[OFF_TGT + t] = (float)tgt;
  }
  slab[tid]  = lab;
  snorm[tid] = nrm;
  __syncthreads();
  float4* srow = (float4*)(out + OFF_SCR + (size_t)base * NCLS);
  int nvec = nrows * (NCLS / 4);
  for (int u = tid; u < nvec; u += 256) {
    int i  = u / (NCLS / 4);
    int c0 = (u - i * (NCLS / 4)) * 4;
    int lb = slab[i]; float nv = snorm[i];
    float4 v;
    v.x = (lb == c0    ) ? nv : 0.f;
    v.y = (lb == c0 + 1) ? nv : 0.f;
    v.z = (lb == c0 + 2) ? nv : 0.f;
    v.w = (lb == c0 + 3) ? nv : 0.f;
    srow[u] = v;
  }
}

extern "C" void kernel_launch(void* const* d_in, const int* in_sizes, int n_in,
                              void* d_out, int out_size, void* d_ws, size_t ws_size,
                              hipStream_t stream)
{
  const float* pd_scores = (const float*)d_in[0];
  const float* pd_bboxes = (const float*)d_in[1];
  const float* anc       = (const float*)d_in[2];
  const int*   gt_labels = (const int*)d_in[3];
  const float* gt_bboxes = (const float*)d_in[4];
  const float* mask_gt   = (const float*)d_in[5];
  int bs = in_sizes[0] / (A_TOT * NCLS);
  int NA = bs * A_TOT, NM = bs * MGT;

  // workspace: every word read is written first -> no memset node
  unsigned long long* pk = (unsigned long long*)d_ws;     // NA (8B-aligned)
  float2* topk_av = (float2*)(pk + NA);                   // NM*TK (8B-aligned)
  int* topk_idx = (int*)(topk_av + NM * TK);              // NM*TK
  unsigned int* pos_al = (unsigned int*)(topk_idx + NM * TK);  // NM
  unsigned int* pos_ov = pos_al + NM;                     // NM

  k_topkA<<<NM, 256, 0, stream>>>(pd_scores, pd_bboxes, anc, gt_labels,
                                  gt_bboxes, mask_gt, topk_idx, topk_av,
                                  pos_al, pos_ov);
  k_resolveB<<<bs * NWIN, BTH, 0, stream>>>(pd_scores, pd_bboxes, gt_labels,
                                            gt_bboxes, topk_idx, topk_av,
                                            pos_al, pos_ov, pk);
  k_writeC<<<(NA + 255) / 256, 256, 0, stream>>>(pk, pos_al, pos_ov, gt_bboxes,
                                                 (float*)d_out, NA);
}